// Round 1
// baseline (579.046 us; speedup 1.0000x reference)
//
#include <hip/hip_runtime.h>
#include <hip/hip_bf16.h>

typedef __attribute__((ext_vector_type(4))) float f32x4;
typedef __attribute__((ext_vector_type(8))) short bfrag;   // 8 bf16 = 4 VGPRs
typedef __attribute__((ext_vector_type(4))) float facc;    // MFMA C/D

#define N_MOVES 200000
#define N_EDGES 1600000
#define DEMB 256
#define KD 512          // 2*D, also layer-2 K
#define H1D 512
#define H2D 256
#define MT 64           // moves per block
#define NTHREADS 512    // 8 waves

__device__ __forceinline__ ushort f2b(float f) {   // f32 -> bf16 RNE
  union { float f; unsigned u; } x; x.f = f;
  unsigned r = (x.u + 0x7fffu + ((x.u >> 16) & 1u)) >> 16;
  return (ushort)r;
}
__device__ __forceinline__ float b2f(ushort h) {
  union { unsigned u; float f; } x; x.u = ((unsigned)h) << 16;
  return x.f;
}

// ---- prep: W1 [512,512] f32 -> bf16 ; W2 [256,512] f32 -> bf16 (into ws) ----
__global__ void convert_w(const float* __restrict__ W1, const float* __restrict__ W2,
                          ushort* __restrict__ Wb) {
  int i = (blockIdx.x * 256 + threadIdx.x) * 4;
  const int n1 = H1D * KD;  // 262144
  if (i < n1) {
    f32x4 v = *(const f32x4*)(W1 + i);
    ushort4 h = { f2b(v.x), f2b(v.y), f2b(v.z), f2b(v.w) };
    *(ushort4*)(Wb + i) = h;
  } else {
    int j = i - n1;          // < 131072
    f32x4 v = *(const f32x4*)(W2 + j);
    ushort4 h = { f2b(v.x), f2b(v.y), f2b(v.z), f2b(v.w) };
    *(ushort4*)(Wb + n1 + j) = h;
  }
}

// ---- fused gather + 3-layer MLP ----
// block: 64 moves, 512 threads (8 waves). LDS ~129KB -> 1 block/CU.
__global__ __launch_bounds__(NTHREADS, 2)
void fused_mlp(const float* __restrict__ emb,
               const int* __restrict__ edge_index,   // [2][N_EDGES]
               const int* __restrict__ move_idx,     // [N_MOVES]
               const ushort* __restrict__ W1b,       // [512][512] bf16
               const float* __restrict__ b1,
               const ushort* __restrict__ W2b,       // [256][512] bf16
               const float* __restrict__ b2,
               const float* __restrict__ W3,         // [256] f32
               const float* __restrict__ b3,
               float* __restrict__ out)
{
  __shared__ ushort bufA[MT][KD];   // 64KB: X (layer1 A), then H2
  __shared__ ushort bufB[MT][KD];   // 64KB: H1 (layer2 A)
  __shared__ int   s_src[MT], s_tgt[MT];
  __shared__ float sW3[H2D];

  const int tid  = threadIdx.x;
  const int lane = tid & 63;
  const int wave = tid >> 6;        // 0..7
  const int m0   = blockIdx.x * MT;

  if (tid < MT) {
    int e = move_idx[m0 + tid];
    s_src[tid] = edge_index[e];
    s_tgt[tid] = edge_index[N_EDGES + e];
  }
  if (tid < H2D) sW3[tid] = W3[tid];
  __syncthreads();

  // ---- gather: X[row][0:256]=emb[src], X[row][256:512]=emb[tgt], f32->bf16, swizzled ----
  for (int u = tid; u < MT * 128; u += NTHREADS) {   // 16 iters, 16B loads
    int row = u >> 7;
    int c4  = u & 127;
    const float* sp = (c4 < 64) ? (emb + (size_t)s_src[row] * DEMB + (c4 << 2))
                                : (emb + (size_t)s_tgt[row] * DEMB + ((c4 - 64) << 2));
    f32x4 v = *(const f32x4*)sp;
    ushort4 h = { f2b(v.x), f2b(v.y), f2b(v.z), f2b(v.w) };
    int bo = (c4 << 3) ^ ((row & 7) << 4);           // XOR swizzle (bank spread)
    *(ushort4*)((char*)(&bufA[row][0]) + bo) = h;
  }
  __syncthreads();

  const int arow = lane & 15;            // M/N index within fragment
  const int ak   = (lane >> 4) << 3;     // k chunk base: 0,8,16,24

  // ================= layer 1: H1[64][512] = relu(X @ W1^T + b1) =================
  // wave owns 64 output cols: n0 = wave*64; acc[4 m-groups][4 n-groups]
  {
    facc acc[4][4] = {};
    const int n0 = wave << 6;
    #pragma unroll 4
    for (int kk = 0; kk < 16; ++kk) {    // K step 32
      bfrag a[4], b[4];
      #pragma unroll
      for (int mg = 0; mg < 4; ++mg) {
        int row = (mg << 4) + arow;
        int bo = ((kk << 6) + (ak << 1)) ^ ((row & 7) << 4);
        a[mg] = *(const bfrag*)((const char*)(&bufA[row][0]) + bo);
      }
      #pragma unroll
      for (int ng = 0; ng < 4; ++ng) {
        int wrow = n0 + (ng << 4) + arow;                  // W1 out-dim row
        b[ng] = *(const bfrag*)(W1b + (size_t)wrow * KD + (kk << 5) + ak);
      }
      #pragma unroll
      for (int mg = 0; mg < 4; ++mg)
        #pragma unroll
        for (int ng = 0; ng < 4; ++ng)
          acc[mg][ng] = __builtin_amdgcn_mfma_f32_16x16x32_bf16(a[mg], b[ng], acc[mg][ng], 0, 0, 0);
    }
    // epilogue: +bias, relu, ->bf16 into bufB (swizzled)
    #pragma unroll
    for (int ng = 0; ng < 4; ++ng) {
      int col = n0 + (ng << 4) + arow;
      float bias = b1[col];
      #pragma unroll
      for (int mg = 0; mg < 4; ++mg) {
        #pragma unroll
        for (int r = 0; r < 4; ++r) {
          int row = (mg << 4) + ((lane >> 4) << 2) + r;    // C/D: row=(lane>>4)*4+r
          float v = fmaxf(acc[mg][ng][r] + bias, 0.f);
          int bo = (col << 1) ^ ((row & 7) << 4);
          *(ushort*)((char*)(&bufB[row][0]) + bo) = f2b(v);
        }
      }
    }
  }
  __syncthreads();

  // ================= layer 2: H2[64][256] = relu(H1 @ W2^T + b2) =================
  ushort (*H2s)[H2D] = (ushort(*)[H2D])bufA;   // reuse X buffer
  {
    facc acc2[4][2] = {};
    const int p0 = wave << 5;                  // 32 cols per wave
    #pragma unroll 4
    for (int kk = 0; kk < 16; ++kk) {
      bfrag a[4], b[2];
      #pragma unroll
      for (int mg = 0; mg < 4; ++mg) {
        int row = (mg << 4) + arow;
        int bo = ((kk << 6) + (ak << 1)) ^ ((row & 7) << 4);
        a[mg] = *(const bfrag*)((const char*)(&bufB[row][0]) + bo);
      }
      #pragma unroll
      for (int ng = 0; ng < 2; ++ng) {
        int wrow = p0 + (ng << 4) + arow;
        b[ng] = *(const bfrag*)(W2b + (size_t)wrow * KD + (kk << 5) + ak);
      }
      #pragma unroll
      for (int mg = 0; mg < 4; ++mg)
        #pragma unroll
        for (int ng = 0; ng < 2; ++ng)
          acc2[mg][ng] = __builtin_amdgcn_mfma_f32_16x16x32_bf16(a[mg], b[ng], acc2[mg][ng], 0, 0, 0);
    }
    #pragma unroll
    for (int ng = 0; ng < 2; ++ng) {
      int col = p0 + (ng << 4) + arow;
      float bias = b2[col];
      #pragma unroll
      for (int mg = 0; mg < 4; ++mg) {
        #pragma unroll
        for (int r = 0; r < 4; ++r) {
          int row = (mg << 4) + ((lane >> 4) << 2) + r;
          float v = fmaxf(acc2[mg][ng][r] + bias, 0.f);
          int bo = (col << 1) ^ ((row & 7) << 4);
          *(ushort*)((char*)(&H2s[row][0]) + bo) = f2b(v);
        }
      }
    }
  }
  __syncthreads();

  // ================= layer 3: out[m] = H2[m] . W3 + b3 (8 lanes per move) =================
  {
    const float b3v = b3[0];
    int row = tid >> 3;          // 0..63
    int oct = tid & 7;           // 32 k's each
    float sum = 0.f;
    #pragma unroll
    for (int j = 0; j < 4; ++j) {
      int kb = (oct << 6) + (j << 4);                 // byte offset of k*2
      int bo = kb ^ ((row & 7) << 4);
      bfrag hv = *(const bfrag*)((const char*)(&H2s[row][0]) + bo);
      int k0 = (oct << 5) + (j << 3);
      #pragma unroll
      for (int e = 0; e < 8; ++e)
        sum += b2f((ushort)hv[e]) * sW3[k0 + e];
    }
    sum += __shfl_xor(sum, 1);
    sum += __shfl_xor(sum, 2);
    sum += __shfl_xor(sum, 4);
    if (oct == 0) out[m0 + row] = sum + b3v;
  }
}

extern "C" void kernel_launch(void* const* d_in, const int* in_sizes, int n_in,
                              void* d_out, int out_size, void* d_ws, size_t ws_size,
                              hipStream_t stream) {
  const float* emb        = (const float*)d_in[0];
  const int*   edge_index = (const int*)d_in[1];
  const int*   move_idx   = (const int*)d_in[2];
  const float* W1         = (const float*)d_in[3];
  const float* b1         = (const float*)d_in[4];
  const float* W2         = (const float*)d_in[5];
  const float* b2         = (const float*)d_in[6];
  const float* W3         = (const float*)d_in[7];
  const float* b3         = (const float*)d_in[8];
  float* out = (float*)d_out;

  ushort* Wb = (ushort*)d_ws;   // W1b [512*512], then W2b [256*512]

  convert_w<<<384, 256, 0, stream>>>(W1, W2, Wb);
  fused_mlp<<<N_MOVES / MT, NTHREADS, 0, stream>>>(
      emb, edge_index, move_idx,
      Wb, b1, Wb + H1D * KD, b2, W3, b3, out);
}